// Round 1
// baseline (605.734 us; speedup 1.0000x reference)
//
#include <hip/hip_runtime.h>
#include <hip/hip_bf16.h>

using bf16 = __bf16;
typedef __bf16 bfx8 __attribute__((ext_vector_type(8)));
typedef float  f32x4 __attribute__((ext_vector_type(4)));

static constexpr int Tt = 2048;
static constexpr int Cm = 1024;   // d_model
static constexpr int NH = 16;
static constexpr int DH = 64;
static constexpr int Bb = 4;
static constexpr int BH = Bb * NH;  // 64

__device__ __forceinline__ void gl_lds16(const void* g, void* lds) {
  __builtin_amdgcn_global_load_lds(
      (const __attribute__((address_space(1))) unsigned int*)g,
      (__attribute__((address_space(3))) unsigned int*)lds, 16, 0, 0);
}

// ---------------- cast fp32 -> bf16 (vectorized) ----------------
__global__ void cast_bf16_kernel(const float* __restrict__ in, bf16* __restrict__ out) {
  int i = blockIdx.x * 256 + threadIdx.x;       // each handles 8 elems
  const float4* p = (const float4*)in + (size_t)i * 2;
  float4 a = p[0], b = p[1];
  bfx8 v;
  v[0] = (bf16)a.x; v[1] = (bf16)a.y; v[2] = (bf16)a.z; v[3] = (bf16)a.w;
  v[4] = (bf16)b.x; v[5] = (bf16)b.y; v[6] = (bf16)b.z; v[7] = (bf16)b.w;
  *((bfx8*)out + i) = v;
}

// ---------------- transpose + cast: in[R][C] f32 -> out[C][R] bf16 ----------------
__global__ void transpose_cast_kernel(const float* __restrict__ in, bf16* __restrict__ out,
                                      int R, int C) {
  __shared__ float tile[32][33];
  int c0 = blockIdx.x * 32, r0 = blockIdx.y * 32;
  int tx = threadIdx.x & 31, ty = threadIdx.x >> 5;  // ty 0..7
#pragma unroll
  for (int i = 0; i < 32; i += 8)
    tile[ty + i][tx] = in[(size_t)(r0 + ty + i) * C + c0 + tx];
  __syncthreads();
#pragma unroll
  for (int i = 0; i < 32; i += 8)
    out[(size_t)(c0 + ty + i) * R + r0 + tx] = (bf16)tile[tx][ty + i];
}

// ---------------- GEMM: C[M][N] = A[M][K] @ Bt[N][K]^T + bias ----------------
// MODE 0: scatter epilogue -> Q (scaled 0.125), K, V^T   (N = 3072)
// MODE 1: plain f32 epilogue -> Cf[M][N]
template <int MODE>
__global__ __launch_bounds__(256, 2)
void gemm_bt(const bf16* __restrict__ A, const bf16* __restrict__ Bt,
             const float* __restrict__ bias, float* __restrict__ Cf,
             bf16* __restrict__ Qo, bf16* __restrict__ Ko, bf16* __restrict__ Vto,
             int M, int N, int K) {
  constexpr int BMt = 128, BNt = 128, BKt = 64;
  __shared__ bf16 Al[BMt * BKt];
  __shared__ bf16 Bl[BNt * BKt];

  const int tid = threadIdx.x;
  const int w = tid >> 6, lane = tid & 63;
  const int lq = lane & 15, lg = lane >> 4;
  const int wm = w >> 1, wn = w & 1;
  const int m0 = blockIdx.x * BMt, n0 = blockIdx.y * BNt;

  f32x4 acc[4][4];
#pragma unroll
  for (int i = 0; i < 4; i++)
#pragma unroll
    for (int j = 0; j < 4; j++) acc[i][j] = (f32x4){0.f, 0.f, 0.f, 0.f};

  for (int k0 = 0; k0 < K; k0 += BKt) {
    // stage A,B tiles: 16KB each; linear LDS dest, XOR-swizzled global source
#pragma unroll
    for (int i = 0; i < 4; ++i) {
      int j = i * 256 + tid;
      int r = j >> 3, c = j & 7;
      int cs = c ^ (r & 7);
      gl_lds16(A + (size_t)(m0 + r) * K + k0 + cs * 8, (char*)Al + j * 16);
      gl_lds16(Bt + (size_t)(n0 + r) * K + k0 + cs * 8, (char*)Bl + j * 16);
    }
    __syncthreads();
#pragma unroll
    for (int kk = 0; kk < 2; ++kk) {
      bfx8 af[4], bfr[4];
#pragma unroll
      for (int mi = 0; mi < 4; ++mi) {
        int r = wm * 64 + mi * 16 + lq;
        int c = kk * 4 + lg;
        af[mi] = *(const bfx8*)((const char*)Al + r * 128 + ((c ^ (r & 7)) * 16));
      }
#pragma unroll
      for (int ni = 0; ni < 4; ++ni) {
        int r = wn * 64 + ni * 16 + lq;
        int c = kk * 4 + lg;
        bfr[ni] = *(const bfx8*)((const char*)Bl + r * 128 + ((c ^ (r & 7)) * 16));
      }
#pragma unroll
      for (int mi = 0; mi < 4; ++mi)
#pragma unroll
        for (int ni = 0; ni < 4; ++ni)
          acc[mi][ni] = __builtin_amdgcn_mfma_f32_16x16x32_bf16(af[mi], bfr[ni], acc[mi][ni], 0, 0, 0);
    }
    __syncthreads();
  }

  // epilogue. C/D layout: col = lane&15, row = (lane>>4)*4 + reg (m89-verified)
#pragma unroll
  for (int mi = 0; mi < 4; ++mi) {
#pragma unroll
    for (int ni = 0; ni < 4; ++ni) {
#pragma unroll
      for (int j = 0; j < 4; ++j) {
        int m = m0 + wm * 64 + mi * 16 + lg * 4 + j;
        int n = n0 + wn * 64 + ni * 16 + lq;
        float v = acc[mi][ni][j] + bias[n];
        if constexpr (MODE == 1) {
          Cf[(size_t)m * N + n] = v;
        } else {
          int sel = n >> 10;          // which of q/k/v
          int c1 = n & 1023;
          int hh = c1 >> 6, dd = c1 & 63;
          int bb = m >> 11, t = m & 2047;
          if (sel == 0) {
            Qo[(((size_t)(bb * NH + hh)) * Tt + t) * DH + dd] = (bf16)(v * 0.125f);
          } else if (sel == 1) {
            Ko[(((size_t)(bb * NH + hh)) * Tt + t) * DH + dd] = (bf16)v;
          } else {
            Vto[(((size_t)(bb * NH + hh)) * DH + dd) * Tt + t] = (bf16)v;
          }
        }
      }
    }
  }
}

// ---------------- causal flash attention ----------------
// Q pre-scaled by 0.125. Q,K: [bh][t][64]; Vt: [bh][64][t]; O: [b][t][1024] bf16
__global__ __launch_bounds__(256, 2)
void attn_fwd(const bf16* __restrict__ Q, const bf16* __restrict__ K,
              const bf16* __restrict__ Vt, bf16* __restrict__ O) {
  const int bh = blockIdx.y;
  const int b = bh >> 4, h = bh & 15;
  const int w = threadIdx.x >> 6, lane = threadIdx.x & 63;
  const int lq = lane & 15, lg = lane >> 4;
  const int q_base = blockIdx.x * 64 + w * 16;

  const bf16* Qp = Q + (size_t)bh * Tt * DH;
  const bf16* Kp = K + (size_t)bh * Tt * DH;
  const bf16* Vp = Vt + (size_t)bh * DH * Tt;

  __shared__ bf16 Pl[4][16][56];   // per-wave P tile, stride 56 (16B-aligned rows)

  // Q fragments (B-operand of swapped QK^T): lane holds q = lane&15, dh = lg*8..+8 (+32)
  bfx8 qf0 = *(const bfx8*)(Qp + (size_t)(q_base + lq) * DH + lg * 8);
  bfx8 qf1 = *(const bfx8*)(Qp + (size_t)(q_base + lq) * DH + 32 + lg * 8);

  f32x4 oacc[4];
#pragma unroll
  for (int i = 0; i < 4; i++) oacc[i] = (f32x4){0.f, 0.f, 0.f, 0.f};
  float m_s = -1e30f, l_s = 0.f;

  const int nk = q_base + 16;  // causal bound for this wave
  for (int k0 = 0; k0 < nk; k0 += 32) {
    f32x4 s[2];
#pragma unroll
    for (int cc = 0; cc < 2; ++cc) {
      int kb = k0 + cc * 16;
      bfx8 kf0 = *(const bfx8*)(Kp + (size_t)(kb + lq) * DH + lg * 8);
      bfx8 kf1 = *(const bfx8*)(Kp + (size_t)(kb + lq) * DH + 32 + lg * 8);
      f32x4 z = (f32x4){0.f, 0.f, 0.f, 0.f};
      z = __builtin_amdgcn_mfma_f32_16x16x32_bf16(kf0, qf0, z, 0, 0, 0);
      z = __builtin_amdgcn_mfma_f32_16x16x32_bf16(kf1, qf1, z, 0, 0, 0);
      s[cc] = z;   // S^T: col = q = lane&15, row = key = lg*4+reg
    }
    // causal mask + row max (per q, across the 4 lane-groups)
    float pm = -1e30f;
#pragma unroll
    for (int cc = 0; cc < 2; ++cc)
#pragma unroll
      for (int j = 0; j < 4; ++j) {
        int key = k0 + cc * 16 + lg * 4 + j;
        if (key > q_base + lq) s[cc][j] = -1e30f;
        pm = fmaxf(pm, s[cc][j]);
      }
    pm = fmaxf(pm, __shfl_xor(pm, 16));
    pm = fmaxf(pm, __shfl_xor(pm, 32));
    float m_new = fmaxf(m_s, pm);
    float fsc = __expf(m_s - m_new);
    float psum = 0.f;
    float p[2][4];
#pragma unroll
    for (int cc = 0; cc < 2; ++cc)
#pragma unroll
      for (int j = 0; j < 4; ++j) {
        p[cc][j] = __expf(s[cc][j] - m_new);
        psum += p[cc][j];
      }
    psum += __shfl_xor(psum, 16);
    psum += __shfl_xor(psum, 32);
    l_s = l_s * fsc + psum;
    m_s = m_new;
    // rescale O accumulator; its rows are q = lg*4 + j -> fetch that row's factor
#pragma unroll
    for (int j = 0; j < 4; ++j) {
      float fq = __shfl(fsc, lg * 4 + j);
#pragma unroll
      for (int n = 0; n < 4; ++n) oacc[n][j] *= fq;
    }
    // P -> LDS transpose: P[q][key_local], bf16 pairs
#pragma unroll
    for (int cc = 0; cc < 2; ++cc)
#pragma unroll
      for (int jj = 0; jj < 4; jj += 2) {
        __hip_bfloat162 pr;
        pr.x = __float2bfloat16(p[cc][jj]);
        pr.y = __float2bfloat16(p[cc][jj + 1]);
        *(__hip_bfloat162*)&Pl[w][lq][cc * 16 + lg * 4 + jj] = pr;
      }
    // PV: A = P (row=q, k=key contiguous), B = V^T rows (col=d, k=key contiguous)
    bfx8 pa = *(const bfx8*)&Pl[w][lq][lg * 8];
#pragma unroll
    for (int n = 0; n < 4; ++n) {
      bfx8 vf = *(const bfx8*)(Vp + (size_t)(n * 16 + lq) * Tt + k0 + lg * 8);
      oacc[n] = __builtin_amdgcn_mfma_f32_16x16x32_bf16(pa, vf, oacc[n], 0, 0, 0);
    }
  }
  // normalize + write O[b][t][h*64 + d]
#pragma unroll
  for (int j = 0; j < 4; ++j) {
    float linv = 1.f / __shfl(l_s, lg * 4 + j);
    int t = q_base + lg * 4 + j;
    size_t base = ((size_t)(b * Tt + t)) * Cm + h * DH;
#pragma unroll
    for (int n = 0; n < 4; ++n)
      O[base + n * 16 + lq] = (bf16)(oacc[n][j] * linv);
  }
}

extern "C" void kernel_launch(void* const* d_in, const int* in_sizes, int n_in,
                              void* d_out, int out_size, void* d_ws, size_t ws_size,
                              hipStream_t stream) {
  const float* x     = (const float*)d_in[0];
  const float* w_qkv = (const float*)d_in[1];
  const float* b_qkv = (const float*)d_in[2];
  const float* w_out = (const float*)d_in[3];
  const float* b_out = (const float*)d_in[4];
  float* out = (float*)d_out;

  const size_t MT = (size_t)Bb * Tt;  // 8192 rows
  bf16* ws    = (bf16*)d_ws;
  bf16* xb    = ws;                                  // 8Mi elems (x bf16; reused as attn out)
  bf16* attn  = xb;                                  // alias (dead after GEMM1)
  bf16* wqkvT = ws + MT * Cm;                        // 3Mi elems [3072][1024]
  bf16* woutT = wqkvT + (size_t)3 * Cm * Cm;         // 1Mi elems [1024][1024]
  bf16* Qb    = woutT + (size_t)Cm * Cm;             // 8Mi
  bf16* Kb    = Qb + (size_t)BH * Tt * DH;           // 8Mi
  bf16* Vtb   = Kb + (size_t)BH * Tt * DH;           // 8Mi

  cast_bf16_kernel<<<dim3((MT * Cm) / (256 * 8)), 256, 0, stream>>>(x, xb);
  transpose_cast_kernel<<<dim3(3 * Cm / 32, Cm / 32), 256, 0, stream>>>(w_qkv, wqkvT, Cm, 3 * Cm);
  transpose_cast_kernel<<<dim3(Cm / 32, Cm / 32), 256, 0, stream>>>(w_out, woutT, Cm, Cm);

  gemm_bt<0><<<dim3(MT / 128, (3 * Cm) / 128), 256, 0, stream>>>(
      xb, wqkvT, b_qkv, nullptr, Qb, Kb, Vtb, (int)MT, 3 * Cm, Cm);

  attn_fwd<<<dim3(Tt / 64, BH), 256, 0, stream>>>(Qb, Kb, Vtb, attn);

  gemm_bt<1><<<dim3(MT / 128, Cm / 128), 256, 0, stream>>>(
      attn, woutT, b_out, out, nullptr, nullptr, nullptr, (int)MT, Cm, Cm);
}

// Round 2
// 337.266 us; speedup vs baseline: 1.7960x; 1.7960x over previous
//
#include <hip/hip_runtime.h>
#include <hip/hip_bf16.h>

using bf16 = __bf16;
typedef __bf16 bfx8 __attribute__((ext_vector_type(8)));
typedef float  f32x4 __attribute__((ext_vector_type(4)));

static constexpr int Tt = 2048;
static constexpr int Cm = 1024;   // d_model
static constexpr int NH = 16;
static constexpr int DH = 64;
static constexpr int Bb = 4;
static constexpr int BH = Bb * NH;  // 64

__device__ __forceinline__ void gl_lds16(const void* g, void* lds) {
  __builtin_amdgcn_global_load_lds(
      (const __attribute__((address_space(1))) unsigned int*)g,
      (__attribute__((address_space(3))) unsigned int*)lds, 16, 0, 0);
}

// ---------------- cast fp32 -> bf16 (vectorized) ----------------
__global__ void cast_bf16_kernel(const float* __restrict__ in, bf16* __restrict__ out) {
  int i = blockIdx.x * 256 + threadIdx.x;       // each handles 8 elems
  const float4* p = (const float4*)in + (size_t)i * 2;
  float4 a = p[0], b = p[1];
  bfx8 v;
  v[0] = (bf16)a.x; v[1] = (bf16)a.y; v[2] = (bf16)a.z; v[3] = (bf16)a.w;
  v[4] = (bf16)b.x; v[5] = (bf16)b.y; v[6] = (bf16)b.z; v[7] = (bf16)b.w;
  *((bfx8*)out + i) = v;
}

// ---------------- transpose + cast: in[R][C] f32 -> out[C][R] bf16 ----------------
__global__ void transpose_cast_kernel(const float* __restrict__ in, bf16* __restrict__ out,
                                      int R, int C) {
  __shared__ float tile[32][33];
  int c0 = blockIdx.x * 32, r0 = blockIdx.y * 32;
  int tx = threadIdx.x & 31, ty = threadIdx.x >> 5;  // ty 0..7
#pragma unroll
  for (int i = 0; i < 32; i += 8)
    tile[ty + i][tx] = in[(size_t)(r0 + ty + i) * C + c0 + tx];
  __syncthreads();
#pragma unroll
  for (int i = 0; i < 32; i += 8)
    out[(size_t)(c0 + ty + i) * R + r0 + tx] = (bf16)tile[tx][ty + i];
}

// ---------------- GEMM: C[M][N] = A[M][K] @ Bt[N][K]^T + bias ----------------
template <int MODE>
__global__ __launch_bounds__(256, 2)
void gemm_bt(const bf16* __restrict__ A, const bf16* __restrict__ Bt,
             const float* __restrict__ bias, float* __restrict__ Cf,
             bf16* __restrict__ Qo, bf16* __restrict__ Ko, bf16* __restrict__ Vto,
             int M, int N, int K) {
  constexpr int BMt = 128, BNt = 128, BKt = 64;
  __shared__ bf16 Al[BMt * BKt];
  __shared__ bf16 Bl[BNt * BKt];

  const int tid = threadIdx.x;
  const int w = tid >> 6, lane = tid & 63;
  const int lq = lane & 15, lg = lane >> 4;
  const int wm = w >> 1, wn = w & 1;
  const int m0 = blockIdx.x * BMt, n0 = blockIdx.y * BNt;

  f32x4 acc[4][4];
#pragma unroll
  for (int i = 0; i < 4; i++)
#pragma unroll
    for (int j = 0; j < 4; j++) acc[i][j] = (f32x4){0.f, 0.f, 0.f, 0.f};

  for (int k0 = 0; k0 < K; k0 += BKt) {
#pragma unroll
    for (int i = 0; i < 4; ++i) {
      int j = i * 256 + tid;
      int r = j >> 3, c = j & 7;
      int cs = c ^ (r & 7);
      gl_lds16(A + (size_t)(m0 + r) * K + k0 + cs * 8, (char*)Al + j * 16);
      gl_lds16(Bt + (size_t)(n0 + r) * K + k0 + cs * 8, (char*)Bl + j * 16);
    }
    __syncthreads();
#pragma unroll
    for (int kk = 0; kk < 2; ++kk) {
      bfx8 af[4], bfr[4];
#pragma unroll
      for (int mi = 0; mi < 4; ++mi) {
        int r = wm * 64 + mi * 16 + lq;
        int c = kk * 4 + lg;
        af[mi] = *(const bfx8*)((const char*)Al + r * 128 + ((c ^ (r & 7)) * 16));
      }
#pragma unroll
      for (int ni = 0; ni < 4; ++ni) {
        int r = wn * 64 + ni * 16 + lq;
        int c = kk * 4 + lg;
        bfr[ni] = *(const bfx8*)((const char*)Bl + r * 128 + ((c ^ (r & 7)) * 16));
      }
#pragma unroll
      for (int mi = 0; mi < 4; ++mi)
#pragma unroll
        for (int ni = 0; ni < 4; ++ni)
          acc[mi][ni] = __builtin_amdgcn_mfma_f32_16x16x32_bf16(af[mi], bfr[ni], acc[mi][ni], 0, 0, 0);
    }
    __syncthreads();
  }

#pragma unroll
  for (int mi = 0; mi < 4; ++mi) {
#pragma unroll
    for (int ni = 0; ni < 4; ++ni) {
#pragma unroll
      for (int j = 0; j < 4; ++j) {
        int m = m0 + wm * 64 + mi * 16 + lg * 4 + j;
        int n = n0 + wn * 64 + ni * 16 + lq;
        float v = acc[mi][ni][j] + bias[n];
        if constexpr (MODE == 1) {
          Cf[(size_t)m * N + n] = v;
        } else {
          int sel = n >> 10;          // which of q/k/v
          int c1 = n & 1023;
          int hh = c1 >> 6, dd = c1 & 63;
          int bb = m >> 11, t = m & 2047;
          if (sel == 0) {
            Qo[(((size_t)(bb * NH + hh)) * Tt + t) * DH + dd] = (bf16)(v * 0.125f);
          } else if (sel == 1) {
            Ko[(((size_t)(bb * NH + hh)) * Tt + t) * DH + dd] = (bf16)v;
          } else {
            Vto[(((size_t)(bb * NH + hh)) * DH + dd) * Tt + t] = (bf16)v;
          }
        }
      }
    }
  }
}

// ---------------- causal flash attention (v2: QBLK=32/wave, KVBLK=64) ----------------
// Q pre-scaled by 0.125. Q,K: [bh][t][64]; Vt: [bh][64][t]; O: [b][t][1024] bf16
__global__ __launch_bounds__(256, 4)
void attn_fwd(const bf16* __restrict__ Q, const bf16* __restrict__ K,
              const bf16* __restrict__ Vt, bf16* __restrict__ O) {
  const int bh = blockIdx.y;
  const int b = bh >> 4, h = bh & 15;
  const int w = threadIdx.x >> 6, lane = threadIdx.x & 63;
  const int lq = lane & 15, lg = lane >> 4;
  // longest strips first (reduce causal tail imbalance)
  const int strip = gridDim.x - 1 - blockIdx.x;
  const int q_base = strip * 128 + w * 32;   // this wave's 32 q rows

  const bf16* Qp = Q + (size_t)bh * Tt * DH;
  const bf16* Kp = K + (size_t)bh * Tt * DH;
  const bf16* Vp = Vt + (size_t)bh * DH * Tt;

  __shared__ bf16 Pl[4][32 * 66];   // per-wave P^T tile: 32 q rows, 64 keys, stride 66
  bf16* Pw = Pl[w];

  // Q fragments (B-operand of swapped QK^T): [q-group][d-half]
  bfx8 qf[2][2];
#pragma unroll
  for (int g = 0; g < 2; ++g)
#pragma unroll
    for (int dh = 0; dh < 2; ++dh)
      qf[g][dh] = *(const bfx8*)(Qp + (size_t)(q_base + g * 16 + lq) * DH + dh * 32 + lg * 8);

  f32x4 oacc[2][4];   // [q-group][d-tile]
#pragma unroll
  for (int g = 0; g < 2; ++g)
#pragma unroll
    for (int n = 0; n < 4; ++n) oacc[g][n] = (f32x4){0.f, 0.f, 0.f, 0.f};
  float m_s[2] = {-3e38f, -3e38f}, l_s[2] = {0.f, 0.f};

  const int kend = q_base + 32;   // causal bound for this wave
  for (int k0 = 0; k0 < kend; k0 += 64) {
    // --- QK^T over 64 keys x 32 q ---
    bfx8 kf[4][2];
#pragma unroll
    for (int cc = 0; cc < 4; ++cc) {
      const bf16* kp = Kp + (size_t)(k0 + cc * 16 + lq) * DH + lg * 8;
      kf[cc][0] = *(const bfx8*)kp;
      kf[cc][1] = *(const bfx8*)(kp + 32);
    }
    f32x4 s[2][4];   // S^T: col = q = lq, row = key = lg*4 + reg
#pragma unroll
    for (int g = 0; g < 2; ++g)
#pragma unroll
      for (int cc = 0; cc < 4; ++cc) {
        f32x4 z = (f32x4){0.f, 0.f, 0.f, 0.f};
        z = __builtin_amdgcn_mfma_f32_16x16x32_bf16(kf[cc][0], qf[g][0], z, 0, 0, 0);
        z = __builtin_amdgcn_mfma_f32_16x16x32_bf16(kf[cc][1], qf[g][1], z, 0, 0, 0);
        s[g][cc] = z;
      }

    const bool diag = (k0 + 64 > q_base);   // wave-uniform: only diagonal blocks mask
    // --- online softmax per q-group ---
#pragma unroll
    for (int g = 0; g < 2; ++g) {
      const int q = q_base + g * 16 + lq;
      if (diag) {
#pragma unroll
        for (int cc = 0; cc < 4; ++cc)
#pragma unroll
          for (int j = 0; j < 4; ++j) {
            int key = k0 + cc * 16 + lg * 4 + j;
            if (key > q) s[g][cc][j] = -3e38f;
          }
      }
      float pm = -3e38f;
#pragma unroll
      for (int cc = 0; cc < 4; ++cc)
#pragma unroll
        for (int j = 0; j < 4; ++j) pm = fmaxf(pm, s[g][cc][j]);
      pm = fmaxf(pm, __shfl_xor(pm, 16));
      pm = fmaxf(pm, __shfl_xor(pm, 32));
      float mn = fmaxf(m_s[g], pm);
      float fsc = __expf(m_s[g] - mn);
      float ps = 0.f;
#pragma unroll
      for (int cc = 0; cc < 4; ++cc)
#pragma unroll
        for (int j = 0; j < 4; ++j) {
          float e = __expf(s[g][cc][j] - mn);
          s[g][cc][j] = e;
          ps += e;
        }
      ps += __shfl_xor(ps, 16);
      ps += __shfl_xor(ps, 32);
      l_s[g] = l_s[g] * fsc + ps;
      m_s[g] = mn;
      // rescale O accumulator rows (row q = lg*4 + j)
#pragma unroll
      for (int j = 0; j < 4; ++j) {
        float fq = __shfl(fsc, lg * 4 + j);
#pragma unroll
        for (int n = 0; n < 4; ++n) oacc[g][n][j] *= fq;
      }
      // pack P^T -> LDS (row = g*16+lq, col = key_local)
#pragma unroll
      for (int cc = 0; cc < 4; ++cc)
#pragma unroll
        for (int jj = 0; jj < 4; jj += 2) {
          __hip_bfloat162 pr;
          pr.x = __float2bfloat16(s[g][cc][jj]);
          pr.y = __float2bfloat16(s[g][cc][jj + 1]);
          *(__hip_bfloat162*)&Pw[(g * 16 + lq) * 66 + cc * 16 + lg * 4 + jj] = pr;
        }
    }

    // --- PV: O[q][d] += P[q][k] * V^T[d][k] ---
#pragma unroll
    for (int c = 0; c < 2; ++c) {
      bfx8 pa[2];
#pragma unroll
      for (int g = 0; g < 2; ++g)
        pa[g] = *(const bfx8*)&Pw[(g * 16 + lq) * 66 + c * 32 + lg * 8];
#pragma unroll
      for (int n = 0; n < 4; ++n) {
        bfx8 vf = *(const bfx8*)(Vp + (size_t)(n * 16 + lq) * Tt + k0 + c * 32 + lg * 8);
#pragma unroll
        for (int g = 0; g < 2; ++g)
          oacc[g][n] = __builtin_amdgcn_mfma_f32_16x16x32_bf16(pa[g], vf, oacc[g][n], 0, 0, 0);
      }
    }
  }

  // --- normalize + write O[b][t][h*64 + d] ---
#pragma unroll
  for (int g = 0; g < 2; ++g)
#pragma unroll
    for (int j = 0; j < 4; ++j) {
      float linv = 1.f / __shfl(l_s[g], lg * 4 + j);
      int t = q_base + g * 16 + lg * 4 + j;
      size_t base = ((size_t)(b * Tt + t)) * Cm + h * DH;
#pragma unroll
      for (int n = 0; n < 4; ++n)
        O[base + n * 16 + lq] = (bf16)(oacc[g][n][j] * linv);
    }
}

extern "C" void kernel_launch(void* const* d_in, const int* in_sizes, int n_in,
                              void* d_out, int out_size, void* d_ws, size_t ws_size,
                              hipStream_t stream) {
  const float* x     = (const float*)d_in[0];
  const float* w_qkv = (const float*)d_in[1];
  const float* b_qkv = (const float*)d_in[2];
  const float* w_out = (const float*)d_in[3];
  const float* b_out = (const float*)d_in[4];
  float* out = (float*)d_out;

  const size_t MT = (size_t)Bb * Tt;  // 8192 rows
  bf16* ws    = (bf16*)d_ws;
  bf16* xb    = ws;                                  // 8Mi elems (x bf16; reused as attn out)
  bf16* attn  = xb;                                  // alias (dead after GEMM1)
  bf16* wqkvT = ws + MT * Cm;                        // 3Mi elems [3072][1024]
  bf16* woutT = wqkvT + (size_t)3 * Cm * Cm;         // 1Mi elems [1024][1024]
  bf16* Qb    = woutT + (size_t)Cm * Cm;             // 8Mi
  bf16* Kb    = Qb + (size_t)BH * Tt * DH;           // 8Mi
  bf16* Vtb   = Kb + (size_t)BH * Tt * DH;           // 8Mi

  cast_bf16_kernel<<<dim3((MT * Cm) / (256 * 8)), 256, 0, stream>>>(x, xb);
  transpose_cast_kernel<<<dim3(3 * Cm / 32, Cm / 32), 256, 0, stream>>>(w_qkv, wqkvT, Cm, 3 * Cm);
  transpose_cast_kernel<<<dim3(Cm / 32, Cm / 32), 256, 0, stream>>>(w_out, woutT, Cm, Cm);

  gemm_bt<0><<<dim3(MT / 128, (3 * Cm) / 128), 256, 0, stream>>>(
      xb, wqkvT, b_qkv, nullptr, Qb, Kb, Vtb, (int)MT, 3 * Cm, Cm);

  attn_fwd<<<dim3(Tt / 128, BH), 256, 0, stream>>>(Qb, Kb, Vtb, attn);

  gemm_bt<1><<<dim3(MT / 128, Cm / 128), 256, 0, stream>>>(
      attn, woutT, b_out, out, nullptr, nullptr, nullptr, (int)MT, Cm, Cm);
}